// Round 2
// baseline (859.683 us; speedup 1.0000x reference)
//
#include <hip/hip_runtime.h>
#include <hip/hip_bf16.h>

__device__ __forceinline__ float sigm(float x) { return 1.f / (1.f + expf(-x)); }
__device__ __forceinline__ float lrelu(float x) { return x > 0.f ? x : 0.2f * x; }
__device__ __forceinline__ float eluf(float x) { return x > 0.f ? x : expf(x) - 1.f; }

#define NEGF (-9e15f)

// ---------------- K1: SingleNodeAttention: h = elu(coef * (feat @ W_sn)) ----------------
// grid 512, block 64
__global__ void k_sn(const float* __restrict__ feat, const float* __restrict__ Wsn,
                     const float* __restrict__ asn, float* __restrict__ h) {
    int n = blockIdx.x, t = threadIdx.x;
    __shared__ float fr[64];
    fr[t] = feat[n * 64 + t];
    __syncthreads();
    float acc = 0.f;
    #pragma unroll 8
    for (int i = 0; i < 64; i++) acc += fr[i] * Wsn[i * 64 + t];
    float p = acc * asn[t];
    #pragma unroll
    for (int off = 32; off >= 1; off >>= 1) p += __shfl_xor(p, off);
    float coef = sigm(lrelu(p));
    h[n * 64 + t] = eluf(coef * acc);
}

// ---------------- K2: global attention 1 -> out[0:64] ----------------
// grid 1, block 512
__global__ void k_gattn1(const float* __restrict__ h, const float* __restrict__ gW,
                         const float* __restrict__ gb, float* __restrict__ out) {
    int t = threadIdx.x;
    __shared__ float sd[512];
    float acc = 0.f;
    for (int i = 0; i < 64; i++) acc += h[t * 64 + i] * gW[i];
    float gate = sigm(acc + gb[0]);
    sd[t] = gate; __syncthreads();
    for (int s = 256; s > 0; s >>= 1) { if (t < s) sd[t] = fmaxf(sd[t], sd[t + s]); __syncthreads(); }
    float m = sd[0]; __syncthreads();
    float p = expf(gate - m);
    sd[t] = p; __syncthreads();
    for (int s = 256; s > 0; s >>= 1) { if (t < s) sd[t] += sd[t + s]; __syncthreads(); }
    float Z = sd[0]; __syncthreads();
    sd[t] = p / Z; __syncthreads();
    if (t < 64) {
        float o = 0.f;
        for (int n = 0; n < 512; n++) o += sd[n] * h[n * 64 + t];
        out[t] = o;
    }
}

// ---------------- K3: GAT1 Wh = h @ Wg, es = Wh.a_src, ed = Wh.a_dst ----------------
// grid (512, 16), block 128
__global__ void k_gat1_wh(const float* __restrict__ h, const float* __restrict__ Wg,
                          const float* __restrict__ asrc, const float* __restrict__ adst,
                          float* __restrict__ Wh, float* __restrict__ es, float* __restrict__ ed) {
    int n = blockIdx.x, hd = blockIdx.y, t = threadIdx.x;
    __shared__ float hr[64];
    __shared__ float r0[2], r1[2];
    if (t < 64) hr[t] = h[n * 64 + t];
    __syncthreads();
    float acc = 0.f;
    const float* W = Wg + (size_t)hd * 64 * 128;
    #pragma unroll 8
    for (int i = 0; i < 64; i++) acc += hr[i] * W[i * 128 + t];
    Wh[(size_t)(hd * 512 + n) * 128 + t] = acc;
    float ps = acc * asrc[hd * 128 + t];
    float pd = acc * adst[hd * 128 + t];
    #pragma unroll
    for (int off = 32; off >= 1; off >>= 1) { ps += __shfl_xor(ps, off); pd += __shfl_xor(pd, off); }
    if ((t & 63) == 0) { r0[t >> 6] = ps; r1[t >> 6] = pd; }
    __syncthreads();
    if (t == 0) { es[hd * 512 + n] = r0[0] + r0[1]; ed[hd * 512 + n] = r1[0] + r1[1]; }
}

// ---------------- K4: ve1[h,i] = sum_o Weg[h,i,o]*a_edge[h,o] ----------------
// grid 16, block 64
__global__ void k_ve1(const float* __restrict__ Weg, const float* __restrict__ ae,
                      float* __restrict__ ve1) {
    int hd = blockIdx.x, i = threadIdx.x;
    float acc = 0.f;
    for (int o = 0; o < 128; o++) acc += Weg[((size_t)hd * 64 + i) * 128 + o] * ae[hd * 128 + o];
    ve1[hd * 64 + i] = acc;
}

// ---------------- K4b: ve2[c] = sum_o Weo[c,o]*ao_edge[o] ----------------
// grid 16, block 128
__global__ void k_ve2(const float* __restrict__ Weo, const float* __restrict__ aoe,
                      float* __restrict__ ve2) {
    int c = blockIdx.x * 128 + threadIdx.x;
    float acc = 0.f;
    for (int o = 0; o < 128; o++) acc += Weo[(size_t)c * 128 + o] * aoe[o];
    ve2[c] = acc;
}

// ---------------- K5: scatter last-wins winner edge per (src/2, dst/2) slot ----------------
// grid 16, block 256
__global__ void k_scatter(const int* __restrict__ ei, int* __restrict__ winner) {
    int e = blockIdx.x * 256 + threadIdx.x;
    if (e < 4096) {
        int s = ei[e] >> 1;
        int d = ei[4096 + e] >> 1;
        atomicMax(&winner[s * 256 + d], e);   // last edge index wins (np .set semantics)
    }
}

// ---------------- K6: GAT1 attention rows, all 16 heads per block ----------------
// grid 512 (s), block 512 (d)
__global__ void k_attn1(const float* __restrict__ es, const float* __restrict__ ed,
                        const float* __restrict__ adj, const float* __restrict__ n2n,
                        const float* __restrict__ ve1, float* __restrict__ attn) {
    int s = blockIdx.x, d = threadIdx.x;
    __shared__ float vl[16][64];
    __shared__ float sd[512];
    __shared__ float esr[16];
    for (int idx = d; idx < 16 * 64; idx += 512) vl[idx >> 6][idx & 63] = ve1[idx];
    if (d < 16) esr[d] = es[d * 512 + s];
    __syncthreads();
    float a = adj[s * 512 + d];
    float e16[16];
    if (a > 0.f) {
        const float* row = n2n + (size_t)(s * 512 + d) * 64;
        float ee[16];
        #pragma unroll
        for (int hd = 0; hd < 16; hd++) ee[hd] = 0.f;
        for (int i = 0; i < 64; i++) {
            float r = row[i];
            #pragma unroll
            for (int hd = 0; hd < 16; hd++) ee[hd] += r * vl[hd][i];
        }
        #pragma unroll
        for (int hd = 0; hd < 16; hd++)
            e16[hd] = lrelu(esr[hd] + ed[hd * 512 + d] + ee[hd]);
    } else {
        #pragma unroll
        for (int hd = 0; hd < 16; hd++) e16[hd] = NEGF;
    }
    #pragma unroll
    for (int hd = 0; hd < 16; hd++) {
        float e = e16[hd];
        sd[d] = e; __syncthreads();
        for (int st = 256; st > 0; st >>= 1) { if (d < st) sd[d] = fmaxf(sd[d], sd[d + st]); __syncthreads(); }
        float m = sd[0]; __syncthreads();
        float p = expf(e - m);
        sd[d] = p; __syncthreads();
        for (int st = 256; st > 0; st >>= 1) { if (d < st) sd[d] += sd[d + st]; __syncthreads(); }
        float Z = sd[0]; __syncthreads();
        attn[((size_t)(hd * 512 + s)) * 512 + d] = p / Z;
    }
}

// ---------------- K7: hout = elu(attn @ Wh), 8 source rows per block ----------------
// grid (64, 16), block 128
__global__ void k_hout1(const float* __restrict__ attn, const float* __restrict__ Wh,
                        float* __restrict__ hout) {
    int st = blockIdx.x, hd = blockIdx.y, t = threadIdx.x;
    __shared__ float at[8][512];
    int s0 = st * 8;
    for (int idx = t; idx < 8 * 512; idx += 128) {
        int r = idx >> 9, d = idx & 511;
        at[r][d] = attn[((size_t)(hd * 512 + s0 + r)) * 512 + d];
    }
    __syncthreads();
    float acc[8] = {0, 0, 0, 0, 0, 0, 0, 0};
    const float* W = Wh + (size_t)hd * 512 * 128;
    for (int d = 0; d < 512; d++) {
        float w = W[(size_t)d * 128 + t];
        #pragma unroll
        for (int r = 0; r < 8; r++) acc[r] += at[r][d] * w;
    }
    #pragma unroll
    for (int r = 0; r < 8; r++)
        hout[(size_t)(s0 + r) * 2048 + hd * 128 + t] = eluf(acc[r]);
}

// ---------------- K8: per-edge d2[e] = sum_c elu(edge_attr[e] @ Weg)[c] * ve2[c] ----------------
// grid 512 (8 edges/block), block 256
__global__ void k_edot(const float* __restrict__ eattr, const float* __restrict__ Weg,
                       const float* __restrict__ ve2, float* __restrict__ d2) {
    int e0 = blockIdx.x * 8, t = threadIdx.x;
    __shared__ float ea[8][64];
    __shared__ float sd[256];
    for (int idx = t; idx < 8 * 64; idx += 256)
        ea[idx >> 6][idx & 63] = eattr[(size_t)(e0 + (idx >> 6)) * 64 + (idx & 63)];
    __syncthreads();
    int hd = t >> 4, o0 = (t & 15) * 8;
    float acc[8][8];
    #pragma unroll
    for (int r = 0; r < 8; r++)
        #pragma unroll
        for (int j = 0; j < 8; j++) acc[r][j] = 0.f;
    const float* W = Weg + (size_t)hd * 64 * 128 + o0;
    for (int i = 0; i < 64; i++) {
        float w[8];
        #pragma unroll
        for (int j = 0; j < 8; j++) w[j] = W[i * 128 + j];
        #pragma unroll
        for (int r = 0; r < 8; r++) {
            float a = ea[r][i];
            #pragma unroll
            for (int j = 0; j < 8; j++) acc[r][j] += a * w[j];
        }
    }
    float v2[8];
    #pragma unroll
    for (int j = 0; j < 8; j++) v2[j] = ve2[hd * 128 + o0 + j];
    for (int r = 0; r < 8; r++) {
        float p = 0.f;
        #pragma unroll
        for (int j = 0; j < 8; j++) p += eluf(acc[r][j]) * v2[j];
        sd[t] = p; __syncthreads();
        for (int st = 128; st > 0; st >>= 1) { if (t < st) sd[t] += sd[t + st]; __syncthreads(); }
        if (t == 0) d2[e0 + r] = sd[0];
        __syncthreads();
    }
}

// ---------------- K9: edge_pool1 ----------------
// grid 256, block 256
__global__ void k_pool1(const float* __restrict__ x, const float* __restrict__ Wp,
                        const float* __restrict__ bp, float* __restrict__ xo) {
    int k = blockIdx.x, t = threadIdx.x;
    __shared__ float sd[256];
    float p = 0.f;
    for (int f = t; f < 2048; f += 256)
        p += x[(size_t)(2 * k) * 2048 + f] * Wp[f] + x[(size_t)(2 * k + 1) * 2048 + f] * Wp[2048 + f];
    sd[t] = p; __syncthreads();
    for (int st = 128; st > 0; st >>= 1) { if (t < st) sd[t] += sd[t + st]; __syncthreads(); }
    float sc = sigm(sd[0] + bp[0]);
    for (int f = t; f < 2048; f += 256)
        xo[(size_t)k * 2048 + f] = (x[(size_t)(2 * k) * 2048 + f] + x[(size_t)(2 * k + 1) * 2048 + f]) * sc;
}

// ---------------- K10: global attention 2 -> out[64:2112] ----------------
// grid 1, block 256
__global__ void k_gattn2(const float* __restrict__ x, const float* __restrict__ gW,
                         const float* __restrict__ gb, float* __restrict__ out) {
    int t = threadIdx.x;
    __shared__ float gsh[256];
    __shared__ float sd[256];
    int w = t >> 6, l = t & 63;
    for (int n = w * 64; n < w * 64 + 64; n++) {
        float a = 0.f;
        for (int c = l; c < 2048; c += 64) a += x[(size_t)n * 2048 + c] * gW[c];
        #pragma unroll
        for (int off = 32; off >= 1; off >>= 1) a += __shfl_xor(a, off);
        if (l == 0) gsh[n] = a;
    }
    __syncthreads();
    float gate = sigm(gsh[t] + gb[0]);
    sd[t] = gate; __syncthreads();
    for (int st = 128; st > 0; st >>= 1) { if (t < st) sd[t] = fmaxf(sd[t], sd[t + st]); __syncthreads(); }
    float m = sd[0]; __syncthreads();
    float p = expf(gate - m);
    sd[t] = p; __syncthreads();
    for (int st = 128; st > 0; st >>= 1) { if (t < st) sd[t] += sd[t + st]; __syncthreads(); }
    float Z = sd[0]; __syncthreads();
    sd[t] = p / Z; __syncthreads();
    float o[8] = {0, 0, 0, 0, 0, 0, 0, 0};
    for (int n = 0; n < 256; n++) {
        float a = sd[n];
        #pragma unroll
        for (int j = 0; j < 8; j++) o[j] += a * x[(size_t)n * 2048 + t + 256 * j];
    }
    #pragma unroll
    for (int j = 0; j < 8; j++) out[64 + t + 256 * j] = o[j];
}

// ---------------- K11: Wh2 = x1p @ Wo, es2/ed2 ----------------
// grid 256, block 128
__global__ void k_wh2(const float* __restrict__ x, const float* __restrict__ Wo,
                      const float* __restrict__ aos, const float* __restrict__ aod,
                      float* __restrict__ Wh2, float* __restrict__ es2, float* __restrict__ ed2) {
    int n = blockIdx.x, t = threadIdx.x;
    __shared__ float xr[2048];
    __shared__ float r0[2], r1[2];
    for (int c = t; c < 2048; c += 128) xr[c] = x[(size_t)n * 2048 + c];
    __syncthreads();
    float acc = 0.f;
    for (int i = 0; i < 2048; i++) acc += xr[i] * Wo[(size_t)i * 128 + t];
    Wh2[n * 128 + t] = acc;
    float ps = acc * aos[t];
    float pd = acc * aod[t];
    #pragma unroll
    for (int off = 32; off >= 1; off >>= 1) { ps += __shfl_xor(ps, off); pd += __shfl_xor(pd, off); }
    if ((t & 63) == 0) { r0[t >> 6] = ps; r1[t >> 6] = pd; }
    __syncthreads();
    if (t == 0) { es2[n] = r0[0] + r0[1]; ed2[n] = r1[0] + r1[1]; }
}

// ---------------- K12: GAT2 attention + hout2 ----------------
// grid 256, block 256
__global__ void k_attn2(const int* __restrict__ winner, const float* __restrict__ d2,
                        const float* __restrict__ es2, const float* __restrict__ ed2,
                        const float* __restrict__ Wh2, float* __restrict__ hout2) {
    int s = blockIdx.x, t = threadIdx.x;
    __shared__ float sd[256];
    __shared__ float at[256];
    int w = winner[s * 256 + t];
    float e;
    if (w >= 0) e = lrelu(es2[s] + ed2[t] + d2[w]);
    else e = NEGF;
    sd[t] = e; __syncthreads();
    for (int st = 128; st > 0; st >>= 1) { if (t < st) sd[t] = fmaxf(sd[t], sd[t + st]); __syncthreads(); }
    float m = sd[0]; __syncthreads();
    float p = expf(e - m);
    sd[t] = p; __syncthreads();
    for (int st = 128; st > 0; st >>= 1) { if (t < st) sd[t] += sd[t + st]; __syncthreads(); }
    float Z = sd[0]; __syncthreads();
    at[t] = p / Z; __syncthreads();
    if (t < 128) {
        float acc = 0.f;
        for (int d = 0; d < 256; d++) acc += at[d] * Wh2[d * 128 + t];
        hout2[s * 128 + t] = acc;   // concat=False: no elu
    }
}

// ---------------- K13: edge_pool2 ----------------
// grid 128, block 128
__global__ void k_pool2(const float* __restrict__ x, const float* __restrict__ Wp,
                        const float* __restrict__ bp, float* __restrict__ xo) {
    int k = blockIdx.x, t = threadIdx.x;
    __shared__ float r[2];
    float a0 = x[(size_t)(2 * k) * 128 + t];
    float a1 = x[(size_t)(2 * k + 1) * 128 + t];
    float p = a0 * Wp[t] + a1 * Wp[128 + t];
    #pragma unroll
    for (int off = 32; off >= 1; off >>= 1) p += __shfl_xor(p, off);
    if ((t & 63) == 0) r[t >> 6] = p;
    __syncthreads();
    float sc = sigm(r[0] + r[1] + bp[0]);
    xo[k * 128 + t] = (a0 + a1) * sc;
}

// ---------------- K14: global attention 3 -> out[2112:2240] ----------------
// grid 1, block 128
__global__ void k_gattn3(const float* __restrict__ x, const float* __restrict__ gW,
                         const float* __restrict__ gb, float* __restrict__ out) {
    int t = threadIdx.x;
    __shared__ float gsh[128];
    __shared__ float sd[128];
    int w = t >> 6, l = t & 63;
    for (int n = w * 64; n < w * 64 + 64; n++) {
        float a = 0.f;
        for (int c = l; c < 128; c += 64) a += x[n * 128 + c] * gW[c];
        #pragma unroll
        for (int off = 32; off >= 1; off >>= 1) a += __shfl_xor(a, off);
        if (l == 0) gsh[n] = a;
    }
    __syncthreads();
    float gate = sigm(gsh[t] + gb[0]);
    sd[t] = gate; __syncthreads();
    for (int st = 64; st > 0; st >>= 1) { if (t < st) sd[t] = fmaxf(sd[t], sd[t + st]); __syncthreads(); }
    float m = sd[0]; __syncthreads();
    float p = expf(gate - m);
    sd[t] = p; __syncthreads();
    for (int st = 64; st > 0; st >>= 1) { if (t < st) sd[t] += sd[t + st]; __syncthreads(); }
    float Z = sd[0]; __syncthreads();
    sd[t] = p / Z; __syncthreads();
    float o = 0.f;
    for (int n = 0; n < 128; n++) o += sd[n] * x[n * 128 + t];
    out[2112 + t] = o;
}

extern "C" void kernel_launch(void* const* d_in, const int* in_sizes, int n_in,
                              void* d_out, int out_size, void* d_ws, size_t ws_size,
                              hipStream_t stream) {
    const float* feat  = (const float*)d_in[0];
    const int*   eidx  = (const int*)d_in[1];
    const float* eattr = (const float*)d_in[2];
    const float* adj   = (const float*)d_in[3];
    const float* n2n   = (const float*)d_in[4];
    const float* Wsn   = (const float*)d_in[5];
    const float* asn   = (const float*)d_in[6];
    const float* Wg    = (const float*)d_in[7];
    const float* Weg   = (const float*)d_in[8];
    const float* asrc  = (const float*)d_in[9];
    const float* adst  = (const float*)d_in[10];
    const float* aedge = (const float*)d_in[11];
    const float* Wp1   = (const float*)d_in[12];
    const float* bp1   = (const float*)d_in[13];
    const float* Wo    = (const float*)d_in[14];
    const float* Weo   = (const float*)d_in[15];
    const float* aos   = (const float*)d_in[16];
    const float* aod   = (const float*)d_in[17];
    const float* aoe   = (const float*)d_in[18];
    const float* Wp2   = (const float*)d_in[19];
    const float* bp2   = (const float*)d_in[20];
    const float* g1W   = (const float*)d_in[21];
    const float* g1b   = (const float*)d_in[22];
    const float* g2W   = (const float*)d_in[23];
    const float* g2b   = (const float*)d_in[24];
    const float* g3W   = (const float*)d_in[25];
    const float* g3b   = (const float*)d_in[26];
    float* out = (float*)d_out;

    char* ws = (char*)d_ws;
    float* h      = (float*)(ws + 0x0000000);   // 512*64*4        = 128KB
    float* Wh1    = (float*)(ws + 0x0020000);   // 16*512*128*4    = 4MB
    float* es1    = (float*)(ws + 0x0420000);   // 16*512*4        = 32KB
    float* ed1    = (float*)(ws + 0x0428000);   // 32KB
    float* ve1    = (float*)(ws + 0x0430000);   // 4KB
    float* ve2    = (float*)(ws + 0x0431000);   // 8KB
    float* attn   = (float*)(ws + 0x0440000);   // 16*512*512*4    = 16MB
    float* hout1  = (float*)(ws + 0x1440000);   // 512*2048*4      = 4MB
    float* d2     = (float*)(ws + 0x1840000);   // 16KB
    float* x1p    = (float*)(ws + 0x1850000);   // 256*2048*4      = 2MB
    int*   winner = (int*)  (ws + 0x1A50000);   // 65536*4         = 256KB
    float* Wh2    = (float*)(ws + 0x1A90000);   // 128KB
    float* es2    = (float*)(ws + 0x1AB0000);   // 1KB
    float* ed2    = (float*)(ws + 0x1AB1000);   // 1KB
    float* hout2  = (float*)(ws + 0x1AB2000);   // 128KB
    float* x2p    = (float*)(ws + 0x1AD2000);   // 64KB
    // total ~28.2MB

    hipMemsetAsync(winner, 0xFF, 65536 * sizeof(int), stream);   // winner = -1

    k_sn     <<<512, 64, 0, stream>>>(feat, Wsn, asn, h);
    k_ve1    <<<16, 64, 0, stream>>>(Weg, aedge, ve1);
    k_ve2    <<<16, 128, 0, stream>>>(Weo, aoe, ve2);
    k_scatter<<<16, 256, 0, stream>>>(eidx, winner);
    k_gattn1 <<<1, 512, 0, stream>>>(h, g1W, g1b, out);
    k_gat1_wh<<<dim3(512, 16), 128, 0, stream>>>(h, Wg, asrc, adst, Wh1, es1, ed1);
    k_attn1  <<<512, 512, 0, stream>>>(es1, ed1, adj, n2n, ve1, attn);
    k_hout1  <<<dim3(64, 16), 128, 0, stream>>>(attn, Wh1, hout1);
    k_edot   <<<512, 256, 0, stream>>>(eattr, Weg, ve2, d2);
    k_pool1  <<<256, 256, 0, stream>>>(hout1, Wp1, bp1, x1p);
    k_gattn2 <<<1, 256, 0, stream>>>(x1p, g2W, g2b, out);
    k_wh2    <<<256, 128, 0, stream>>>(x1p, Wo, aos, aod, Wh2, es2, ed2);
    k_attn2  <<<256, 256, 0, stream>>>(winner, d2, es2, ed2, Wh2, hout2);
    k_pool2  <<<128, 128, 0, stream>>>(hout2, Wp2, bp2, x2p);
    k_gattn3 <<<1, 128, 0, stream>>>(x2p, g3W, g3b, out);
}

// Round 3
// 203.390 us; speedup vs baseline: 4.2268x; 4.2268x over previous
//
#include <hip/hip_runtime.h>
#include <hip/hip_bf16.h>

__device__ __forceinline__ float sigm(float x) { return 1.f / (1.f + expf(-x)); }
__device__ __forceinline__ float lrelu(float x) { return x > 0.f ? x : 0.2f * x; }
__device__ __forceinline__ float eluf(float x) { return x > 0.f ? x : expf(x) - 1.f; }

#define NEGF (-9e15f)

__device__ __forceinline__ float wave_sum(float v) {
    #pragma unroll
    for (int off = 32; off >= 1; off >>= 1) v += __shfl_xor(v, off);
    return v;
}
__device__ __forceinline__ float wave_max(float v) {
    #pragma unroll
    for (int off = 32; off >= 1; off >>= 1) v = fmaxf(v, __shfl_xor(v, off));
    return v;
}

// ---------------- K1: SingleNodeAttention: h = elu(coef * (feat @ W_sn)) ----------------
// grid 512, block 64
__global__ void k_sn(const float* __restrict__ feat, const float* __restrict__ Wsn,
                     const float* __restrict__ asn, float* __restrict__ h) {
    int n = blockIdx.x, t = threadIdx.x;
    __shared__ float fr[64];
    fr[t] = feat[n * 64 + t];
    __syncthreads();
    float acc = 0.f;
    #pragma unroll 8
    for (int i = 0; i < 64; i++) acc += fr[i] * Wsn[i * 64 + t];
    float p = wave_sum(acc * asn[t]);
    float coef = sigm(lrelu(p));
    h[n * 64 + t] = eluf(coef * acc);
}

// ---------------- gate1[n] = sigm(h[n]·g1W + b), wave per node ----------------
// grid 128, block 256
__global__ void k_gate1(const float* __restrict__ h, const float* __restrict__ gW,
                        const float* __restrict__ gb, float* __restrict__ gate) {
    int node = blockIdx.x * 4 + (threadIdx.x >> 6), l = threadIdx.x & 63;
    float v = wave_sum(h[node * 64 + l] * gW[l]);
    if (l == 0) gate[node] = sigm(v + gb[0]);
}

// ---------------- wsum1: out[0:64] = sum_n softmax(gate1)[n] * h[n,:] ----------------
// grid 1, block 512
__global__ void k_wsum1(const float* __restrict__ h, const float* __restrict__ gate,
                        float* __restrict__ out) {
    int t = threadIdx.x, w = t >> 6, l = t & 63;
    __shared__ float mx[8], sm[8], al[512], part[8][64];
    float g = gate[t];
    float m = wave_max(g);
    if (l == 0) mx[w] = m;
    __syncthreads();
    m = mx[0];
    #pragma unroll
    for (int i = 1; i < 8; i++) m = fmaxf(m, mx[i]);
    float p = expf(g - m);
    float Z = wave_sum(p);
    if (l == 0) sm[w] = Z;
    __syncthreads();
    Z = 0.f;
    #pragma unroll
    for (int i = 0; i < 8; i++) Z += sm[i];
    al[t] = p / Z;
    __syncthreads();
    float acc = 0.f;
    for (int k = 0; k < 64; k++) {
        int n = w * 64 + k;
        acc += al[n] * h[n * 64 + l];
    }
    part[w][l] = acc;
    __syncthreads();
    if (t < 64) {
        float o = 0.f;
        #pragma unroll
        for (int g2 = 0; g2 < 8; g2++) o += part[g2][t];
        out[t] = o;
    }
}

// ---------------- K3: GAT1 Wh = h @ Wg, es = Wh.a_src, ed = Wh.a_dst ----------------
// grid (512, 16), block 128
__global__ void k_gat1_wh(const float* __restrict__ h, const float* __restrict__ Wg,
                          const float* __restrict__ asrc, const float* __restrict__ adst,
                          float* __restrict__ Wh, float* __restrict__ es, float* __restrict__ ed) {
    int n = blockIdx.x, hd = blockIdx.y, t = threadIdx.x;
    __shared__ float hr[64];
    __shared__ float r0[2], r1[2];
    if (t < 64) hr[t] = h[n * 64 + t];
    __syncthreads();
    float acc = 0.f;
    const float* W = Wg + (size_t)hd * 64 * 128;
    #pragma unroll 8
    for (int i = 0; i < 64; i++) acc += hr[i] * W[i * 128 + t];
    Wh[(size_t)(hd * 512 + n) * 128 + t] = acc;
    float ps = wave_sum(acc * asrc[hd * 128 + t]);
    float pd = wave_sum(acc * adst[hd * 128 + t]);
    if ((t & 63) == 0) { r0[t >> 6] = ps; r1[t >> 6] = pd; }
    __syncthreads();
    if (t == 0) { es[hd * 512 + n] = r0[0] + r0[1]; ed[hd * 512 + n] = r1[0] + r1[1]; }
}

// ---------------- K4: ve1[h,i] = sum_o Weg[h,i,o]*a_edge[h,o] ----------------
// grid 16, block 64
__global__ void k_ve1(const float* __restrict__ Weg, const float* __restrict__ ae,
                      float* __restrict__ ve1) {
    int hd = blockIdx.x, i = threadIdx.x;
    float acc = 0.f;
    for (int o = 0; o < 128; o++) acc += Weg[((size_t)hd * 64 + i) * 128 + o] * ae[hd * 128 + o];
    ve1[hd * 64 + i] = acc;
}

// ---------------- K4b: ve2[c] = sum_o Weo[c,o]*ao_edge[o] ----------------
// grid 16, block 128
__global__ void k_ve2(const float* __restrict__ Weo, const float* __restrict__ aoe,
                      float* __restrict__ ve2) {
    int c = blockIdx.x * 128 + threadIdx.x;
    float acc = 0.f;
    for (int o = 0; o < 128; o++) acc += Weo[(size_t)c * 128 + o] * aoe[o];
    ve2[c] = acc;
}

// ---------------- K5: scatter last-wins winner edge per (src/2, dst/2) slot ----------------
// grid 16, block 256
__global__ void k_scatter(const int* __restrict__ ei, int* __restrict__ winner) {
    int e = blockIdx.x * 256 + threadIdx.x;
    if (e < 4096) {
        int s = ei[e] >> 1;
        int d = ei[4096 + e] >> 1;
        atomicMax(&winner[s * 256 + d], e);   // last edge index wins (np .set semantics)
    }
}

// ---------------- K6: GAT1 attention rows, wave-parallel softmax (2 heads/wave) ----------------
// grid 512 (s), block 512
__global__ void k_attn1(const float* __restrict__ es, const float* __restrict__ ed,
                        const float* __restrict__ adj, const float* __restrict__ n2n,
                        const float* __restrict__ ve1, float* __restrict__ attn) {
    int s = blockIdx.x, d = threadIdx.x;
    __shared__ float vl[16][64];     // 4KB
    __shared__ float esh[16][512];   // 32KB
    __shared__ float esr[16];
    for (int idx = d; idx < 16 * 64; idx += 512) vl[idx >> 6][idx & 63] = ve1[idx];
    if (d < 16) esr[d] = es[d * 512 + s];
    __syncthreads();
    float a = adj[s * 512 + d];
    if (a > 0.f) {
        const float* row = n2n + (size_t)(s * 512 + d) * 64;
        float ee[16];
        #pragma unroll
        for (int hd = 0; hd < 16; hd++) ee[hd] = 0.f;
        for (int i = 0; i < 64; i++) {
            float r = row[i];
            #pragma unroll
            for (int hd = 0; hd < 16; hd++) ee[hd] += r * vl[hd][i];
        }
        #pragma unroll
        for (int hd = 0; hd < 16; hd++)
            esh[hd][d] = lrelu(esr[hd] + ed[hd * 512 + d] + ee[hd]);
    } else {
        #pragma unroll
        for (int hd = 0; hd < 16; hd++) esh[hd][d] = NEGF;
    }
    __syncthreads();
    int w = d >> 6, l = d & 63;
    #pragma unroll
    for (int j = 0; j < 2; j++) {
        int hd = 2 * w + j;
        float v[8];
        #pragma unroll
        for (int k = 0; k < 8; k++) v[k] = esh[hd][l + 64 * k];
        float m = v[0];
        #pragma unroll
        for (int k = 1; k < 8; k++) m = fmaxf(m, v[k]);
        m = wave_max(m);
        float p[8], Z = 0.f;
        #pragma unroll
        for (int k = 0; k < 8; k++) { p[k] = expf(v[k] - m); Z += p[k]; }
        Z = wave_sum(Z);
        float inv = 1.f / Z;
        float* dst = attn + ((size_t)(hd * 512 + s)) * 512;
        #pragma unroll
        for (int k = 0; k < 8; k++) dst[l + 64 * k] = p[k] * inv;
    }
}

// ---------------- K7: hout = elu(attn @ Wh), 8 source rows per block ----------------
// grid (64, 16), block 128
__global__ void k_hout1(const float* __restrict__ attn, const float* __restrict__ Wh,
                        float* __restrict__ hout) {
    int st = blockIdx.x, hd = blockIdx.y, t = threadIdx.x;
    __shared__ float at[8][512];
    int s0 = st * 8;
    for (int idx = t; idx < 8 * 512; idx += 128) {
        int r = idx >> 9, d = idx & 511;
        at[r][d] = attn[((size_t)(hd * 512 + s0 + r)) * 512 + d];
    }
    __syncthreads();
    float acc[8] = {0, 0, 0, 0, 0, 0, 0, 0};
    const float* W = Wh + (size_t)hd * 512 * 128;
    for (int d = 0; d < 512; d++) {
        float w = W[(size_t)d * 128 + t];
        #pragma unroll
        for (int r = 0; r < 8; r++) acc[r] += at[r][d] * w;
    }
    #pragma unroll
    for (int r = 0; r < 8; r++)
        hout[(size_t)(s0 + r) * 2048 + hd * 128 + t] = eluf(acc[r]);
}

// ---------------- K8: per-edge d2[e] = sum_c elu(edge_attr[e] @ Weg)[c] * ve2[c] ----------------
// grid 512 (8 edges/block), block 256
__global__ void k_edot(const float* __restrict__ eattr, const float* __restrict__ Weg,
                       const float* __restrict__ ve2, float* __restrict__ d2) {
    int e0 = blockIdx.x * 8, t = threadIdx.x;
    int w = t >> 6, l = t & 63;
    __shared__ float ea[8][64];
    __shared__ float sd[8][4];
    for (int idx = t; idx < 8 * 64; idx += 256)
        ea[idx >> 6][idx & 63] = eattr[(size_t)(e0 + (idx >> 6)) * 64 + (idx & 63)];
    __syncthreads();
    int hd = t >> 4, o0 = (t & 15) * 8;
    float acc[8][8];
    #pragma unroll
    for (int r = 0; r < 8; r++)
        #pragma unroll
        for (int j = 0; j < 8; j++) acc[r][j] = 0.f;
    const float* W = Weg + (size_t)hd * 64 * 128 + o0;
    for (int i = 0; i < 64; i++) {
        float wv[8];
        #pragma unroll
        for (int j = 0; j < 8; j++) wv[j] = W[i * 128 + j];
        #pragma unroll
        for (int r = 0; r < 8; r++) {
            float a = ea[r][i];
            #pragma unroll
            for (int j = 0; j < 8; j++) acc[r][j] += a * wv[j];
        }
    }
    float v2[8];
    #pragma unroll
    for (int j = 0; j < 8; j++) v2[j] = ve2[hd * 128 + o0 + j];
    #pragma unroll
    for (int r = 0; r < 8; r++) {
        float p = 0.f;
        #pragma unroll
        for (int j = 0; j < 8; j++) p += eluf(acc[r][j]) * v2[j];
        p = wave_sum(p);
        if (l == 0) sd[r][w] = p;
    }
    __syncthreads();
    if (t < 8) d2[e0 + t] = sd[t][0] + sd[t][1] + sd[t][2] + sd[t][3];
}

// ---------------- K9: edge_pool1 ----------------
// grid 256, block 256
__global__ void k_pool1(const float* __restrict__ x, const float* __restrict__ Wp,
                        const float* __restrict__ bp, float* __restrict__ xo) {
    int k = blockIdx.x, t = threadIdx.x, w = t >> 6, l = t & 63;
    __shared__ float sd[4];
    float p = 0.f;
    for (int f = t; f < 2048; f += 256)
        p += x[(size_t)(2 * k) * 2048 + f] * Wp[f] + x[(size_t)(2 * k + 1) * 2048 + f] * Wp[2048 + f];
    p = wave_sum(p);
    if (l == 0) sd[w] = p;
    __syncthreads();
    float sc = sigm(sd[0] + sd[1] + sd[2] + sd[3] + bp[0]);
    for (int f = t; f < 2048; f += 256)
        xo[(size_t)k * 2048 + f] = (x[(size_t)(2 * k) * 2048 + f] + x[(size_t)(2 * k + 1) * 2048 + f]) * sc;
}

// ---------------- gate2[n] = sigm(x1p[n]·g2W + b), block per node ----------------
// grid 256, block 256
__global__ void k_gate2(const float* __restrict__ x, const float* __restrict__ gW,
                        const float* __restrict__ gb, float* __restrict__ gate) {
    int n = blockIdx.x, t = threadIdx.x, w = t >> 6, l = t & 63;
    __shared__ float sd[4];
    float p = 0.f;
    #pragma unroll
    for (int k = 0; k < 8; k++) {
        int c = t + 256 * k;
        p += x[(size_t)n * 2048 + c] * gW[c];
    }
    p = wave_sum(p);
    if (l == 0) sd[w] = p;
    __syncthreads();
    if (t == 0) gate[n] = sigm(sd[0] + sd[1] + sd[2] + sd[3] + gb[0]);
}

// ---------------- wsum2: out[64+c] = sum_n softmax(gate2)[n]*x[n,c] ----------------
// grid 8, block 256
__global__ void k_wsum2(const float* __restrict__ x, const float* __restrict__ gate,
                        float* __restrict__ out) {
    int t = threadIdx.x, w = t >> 6, l = t & 63;
    __shared__ float mx[4], sm[4], al[256];
    float g = gate[t];
    float m = wave_max(g);
    if (l == 0) mx[w] = m;
    __syncthreads();
    m = fmaxf(fmaxf(mx[0], mx[1]), fmaxf(mx[2], mx[3]));
    float p = expf(g - m);
    float Z = wave_sum(p);
    if (l == 0) sm[w] = Z;
    __syncthreads();
    Z = sm[0] + sm[1] + sm[2] + sm[3];
    al[t] = p / Z;
    __syncthreads();
    int c = blockIdx.x * 256 + t;
    float acc = 0.f;
    for (int n = 0; n < 256; n++) acc += al[n] * x[(size_t)n * 2048 + c];
    out[64 + c] = acc;
}

// ---------------- K11: Wh2 = x1p @ Wo, es2/ed2 ----------------
// grid 256, block 128
__global__ void k_wh2(const float* __restrict__ x, const float* __restrict__ Wo,
                      const float* __restrict__ aos, const float* __restrict__ aod,
                      float* __restrict__ Wh2, float* __restrict__ es2, float* __restrict__ ed2) {
    int n = blockIdx.x, t = threadIdx.x;
    __shared__ float xr[2048];
    __shared__ float r0[2], r1[2];
    for (int c = t; c < 2048; c += 128) xr[c] = x[(size_t)n * 2048 + c];
    __syncthreads();
    float acc = 0.f;
    for (int i = 0; i < 2048; i++) acc += xr[i] * Wo[(size_t)i * 128 + t];
    Wh2[n * 128 + t] = acc;
    float ps = wave_sum(acc * aos[t]);
    float pd = wave_sum(acc * aod[t]);
    if ((t & 63) == 0) { r0[t >> 6] = ps; r1[t >> 6] = pd; }
    __syncthreads();
    if (t == 0) { es2[n] = r0[0] + r0[1]; ed2[n] = r1[0] + r1[1]; }
}

// ---------------- K12: GAT2 attention + hout2 ----------------
// grid 256, block 256
__global__ void k_attn2(const int* __restrict__ winner, const float* __restrict__ d2,
                        const float* __restrict__ es2, const float* __restrict__ ed2,
                        const float* __restrict__ Wh2, float* __restrict__ hout2) {
    int s = blockIdx.x, t = threadIdx.x, w = t >> 6, l = t & 63;
    __shared__ float mx[4], sm[4], at[256];
    int win = winner[s * 256 + t];
    float e;
    if (win >= 0) e = lrelu(es2[s] + ed2[t] + d2[win]);
    else e = NEGF;
    float m = wave_max(e);
    if (l == 0) mx[w] = m;
    __syncthreads();
    m = fmaxf(fmaxf(mx[0], mx[1]), fmaxf(mx[2], mx[3]));
    float p = expf(e - m);
    float Z = wave_sum(p);
    if (l == 0) sm[w] = Z;
    __syncthreads();
    Z = sm[0] + sm[1] + sm[2] + sm[3];
    at[t] = p / Z;
    __syncthreads();
    if (t < 128) {
        float acc = 0.f;
        for (int d = 0; d < 256; d++) acc += at[d] * Wh2[d * 128 + t];
        hout2[s * 128 + t] = acc;   // concat=False: no elu
    }
}

// ---------------- K13: edge_pool2 ----------------
// grid 128, block 128
__global__ void k_pool2(const float* __restrict__ x, const float* __restrict__ Wp,
                        const float* __restrict__ bp, float* __restrict__ xo) {
    int k = blockIdx.x, t = threadIdx.x;
    __shared__ float r[2];
    float a0 = x[(size_t)(2 * k) * 128 + t];
    float a1 = x[(size_t)(2 * k + 1) * 128 + t];
    float p = wave_sum(a0 * Wp[t] + a1 * Wp[128 + t]);
    if ((t & 63) == 0) r[t >> 6] = p;
    __syncthreads();
    float sc = sigm(r[0] + r[1] + bp[0]);
    xo[k * 128 + t] = (a0 + a1) * sc;
}

// ---------------- gate3[n] = sigm(x2p[n]·g3W + b), wave per node ----------------
// grid 32, block 256
__global__ void k_gate3(const float* __restrict__ x, const float* __restrict__ gW,
                        const float* __restrict__ gb, float* __restrict__ gate) {
    int node = blockIdx.x * 4 + (threadIdx.x >> 6), l = threadIdx.x & 63;
    float v = x[node * 128 + l] * gW[l] + x[node * 128 + 64 + l] * gW[64 + l];
    v = wave_sum(v);
    if (l == 0) gate[node] = sigm(v + gb[0]);
}

// ---------------- wsum3: out[2112+c] = sum_n softmax(gate3)[n]*x[n,c] ----------------
// grid 1, block 128
__global__ void k_wsum3(const float* __restrict__ x, const float* __restrict__ gate,
                        float* __restrict__ out) {
    int t = threadIdx.x, w = t >> 6, l = t & 63;
    __shared__ float mx[2], sm[2], al[128];
    float g = gate[t];
    float m = wave_max(g);
    if (l == 0) mx[w] = m;
    __syncthreads();
    m = fmaxf(mx[0], mx[1]);
    float p = expf(g - m);
    float Z = wave_sum(p);
    if (l == 0) sm[w] = Z;
    __syncthreads();
    Z = sm[0] + sm[1];
    al[t] = p / Z;
    __syncthreads();
    float acc = 0.f;
    for (int n = 0; n < 128; n++) acc += al[n] * x[n * 128 + t];
    out[2112 + t] = acc;
}

extern "C" void kernel_launch(void* const* d_in, const int* in_sizes, int n_in,
                              void* d_out, int out_size, void* d_ws, size_t ws_size,
                              hipStream_t stream) {
    const float* feat  = (const float*)d_in[0];
    const int*   eidx  = (const int*)d_in[1];
    const float* eattr = (const float*)d_in[2];
    const float* adj   = (const float*)d_in[3];
    const float* n2n   = (const float*)d_in[4];
    const float* Wsn   = (const float*)d_in[5];
    const float* asn   = (const float*)d_in[6];
    const float* Wg    = (const float*)d_in[7];
    const float* Weg   = (const float*)d_in[8];
    const float* asrc  = (const float*)d_in[9];
    const float* adst  = (const float*)d_in[10];
    const float* aedge = (const float*)d_in[11];
    const float* Wp1   = (const float*)d_in[12];
    const float* bp1   = (const float*)d_in[13];
    const float* Wo    = (const float*)d_in[14];
    const float* Weo   = (const float*)d_in[15];
    const float* aos   = (const float*)d_in[16];
    const float* aod   = (const float*)d_in[17];
    const float* aoe   = (const float*)d_in[18];
    const float* Wp2   = (const float*)d_in[19];
    const float* bp2   = (const float*)d_in[20];
    const float* g1W   = (const float*)d_in[21];
    const float* g1b   = (const float*)d_in[22];
    const float* g2W   = (const float*)d_in[23];
    const float* g2b   = (const float*)d_in[24];
    const float* g3W   = (const float*)d_in[25];
    const float* g3b   = (const float*)d_in[26];
    float* out = (float*)d_out;

    char* ws = (char*)d_ws;
    float* h      = (float*)(ws + 0x0000000);   // 128KB
    float* Wh1    = (float*)(ws + 0x0020000);   // 4MB
    float* es1    = (float*)(ws + 0x0420000);   // 32KB
    float* ed1    = (float*)(ws + 0x0428000);   // 32KB
    float* ve1    = (float*)(ws + 0x0430000);   // 4KB
    float* ve2    = (float*)(ws + 0x0431000);   // 8KB
    float* gate1  = (float*)(ws + 0x0433000);   // 2KB
    float* gate2  = (float*)(ws + 0x0434000);   // 1KB
    float* gate3  = (float*)(ws + 0x0435000);   // 0.5KB
    float* attn   = (float*)(ws + 0x0440000);   // 16MB
    float* hout1  = (float*)(ws + 0x1440000);   // 4MB
    float* d2     = (float*)(ws + 0x1840000);   // 16KB
    float* x1p    = (float*)(ws + 0x1850000);   // 2MB
    int*   winner = (int*)  (ws + 0x1A50000);   // 256KB
    float* Wh2    = (float*)(ws + 0x1A90000);   // 128KB
    float* es2    = (float*)(ws + 0x1AB0000);   // 1KB
    float* ed2    = (float*)(ws + 0x1AB1000);   // 1KB
    float* hout2  = (float*)(ws + 0x1AB2000);   // 128KB
    float* x2p    = (float*)(ws + 0x1AD2000);   // 64KB

    hipMemsetAsync(winner, 0xFF, 65536 * sizeof(int), stream);   // winner = -1

    k_sn     <<<512, 64, 0, stream>>>(feat, Wsn, asn, h);
    k_ve1    <<<16, 64, 0, stream>>>(Weg, aedge, ve1);
    k_ve2    <<<16, 128, 0, stream>>>(Weo, aoe, ve2);
    k_scatter<<<16, 256, 0, stream>>>(eidx, winner);
    k_gate1  <<<128, 256, 0, stream>>>(h, g1W, g1b, gate1);
    k_wsum1  <<<1, 512, 0, stream>>>(h, gate1, out);
    k_gat1_wh<<<dim3(512, 16), 128, 0, stream>>>(h, Wg, asrc, adst, Wh1, es1, ed1);
    k_attn1  <<<512, 512, 0, stream>>>(es1, ed1, adj, n2n, ve1, attn);
    k_hout1  <<<dim3(64, 16), 128, 0, stream>>>(attn, Wh1, hout1);
    k_edot   <<<512, 256, 0, stream>>>(eattr, Weg, ve2, d2);
    k_pool1  <<<256, 256, 0, stream>>>(hout1, Wp1, bp1, x1p);
    k_gate2  <<<256, 256, 0, stream>>>(x1p, g2W, g2b, gate2);
    k_wsum2  <<<8, 256, 0, stream>>>(x1p, gate2, out);
    k_wh2    <<<256, 128, 0, stream>>>(x1p, Wo, aos, aod, Wh2, es2, ed2);
    k_attn2  <<<256, 256, 0, stream>>>(winner, d2, es2, ed2, Wh2, hout2);
    k_pool2  <<<128, 128, 0, stream>>>(hout2, Wp2, bp2, x2p);
    k_gate3  <<<32, 256, 0, stream>>>(x2p, g3W, g3b, gate3);
    k_wsum3  <<<1, 128, 0, stream>>>(x2p, gate3, out);
}

// Round 4
// 172.052 us; speedup vs baseline: 4.9967x; 1.1821x over previous
//
#include <hip/hip_runtime.h>
#include <hip/hip_bf16.h>

__device__ __forceinline__ float sigm(float x) { return 1.f / (1.f + expf(-x)); }
__device__ __forceinline__ float lrelu(float x) { return x > 0.f ? x : 0.2f * x; }
__device__ __forceinline__ float eluf(float x) { return x > 0.f ? x : expf(x) - 1.f; }

#define NEGF (-9e15f)

__device__ __forceinline__ float wave_sum(float v) {
    #pragma unroll
    for (int off = 32; off >= 1; off >>= 1) v += __shfl_xor(v, off);
    return v;
}
__device__ __forceinline__ float wave_max(float v) {
    #pragma unroll
    for (int off = 32; off >= 1; off >>= 1) v = fmaxf(v, __shfl_xor(v, off));
    return v;
}

// ---------------- K1: SingleNodeAttention: h = elu(coef * (feat @ W_sn)) ----------------
// grid 512, block 64
__global__ void k_sn(const float* __restrict__ feat, const float* __restrict__ Wsn,
                     const float* __restrict__ asn, float* __restrict__ h) {
    int n = blockIdx.x, t = threadIdx.x;
    __shared__ float fr[64];
    fr[t] = feat[n * 64 + t];
    __syncthreads();
    float acc = 0.f;
    #pragma unroll 8
    for (int i = 0; i < 64; i++) acc += fr[i] * Wsn[i * 64 + t];
    float p = wave_sum(acc * asn[t]);
    float coef = sigm(lrelu(p));
    h[n * 64 + t] = eluf(coef * acc);
}

// ---------------- gate1[n] = sigm(h[n]·g1W + b), wave per node ----------------
// grid 128, block 256
__global__ void k_gate1(const float* __restrict__ h, const float* __restrict__ gW,
                        const float* __restrict__ gb, float* __restrict__ gate) {
    int node = blockIdx.x * 4 + (threadIdx.x >> 6), l = threadIdx.x & 63;
    float v = wave_sum(h[node * 64 + l] * gW[l]);
    if (l == 0) gate[node] = sigm(v + gb[0]);
}

// ---------------- wsum1: out[0:64] = sum_n softmax(gate1)[n] * h[n,:] ----------------
// grid 1, block 512
__global__ void k_wsum1(const float* __restrict__ h, const float* __restrict__ gate,
                        float* __restrict__ out) {
    int t = threadIdx.x, w = t >> 6, l = t & 63;
    __shared__ float mx[8], sm[8], al[512], part[8][64];
    float g = gate[t];
    float m = wave_max(g);
    if (l == 0) mx[w] = m;
    __syncthreads();
    m = mx[0];
    #pragma unroll
    for (int i = 1; i < 8; i++) m = fmaxf(m, mx[i]);
    float p = expf(g - m);
    float Z = wave_sum(p);
    if (l == 0) sm[w] = Z;
    __syncthreads();
    Z = 0.f;
    #pragma unroll
    for (int i = 0; i < 8; i++) Z += sm[i];
    al[t] = p / Z;
    __syncthreads();
    float acc = 0.f;
    for (int k = 0; k < 64; k++) {
        int n = w * 64 + k;
        acc += al[n] * h[n * 64 + l];
    }
    part[w][l] = acc;
    __syncthreads();
    if (t < 64) {
        float o = 0.f;
        #pragma unroll
        for (int g2 = 0; g2 < 8; g2++) o += part[g2][t];
        out[t] = o;
    }
}

// ---------------- K3: GAT1 Wh = h @ Wg, es = Wh.a_src, ed = Wh.a_dst ----------------
// grid (512, 16), block 128
__global__ void k_gat1_wh(const float* __restrict__ h, const float* __restrict__ Wg,
                          const float* __restrict__ asrc, const float* __restrict__ adst,
                          float* __restrict__ Wh, float* __restrict__ es, float* __restrict__ ed) {
    int n = blockIdx.x, hd = blockIdx.y, t = threadIdx.x;
    __shared__ float hr[64];
    __shared__ float r0[2], r1[2];
    if (t < 64) hr[t] = h[n * 64 + t];
    __syncthreads();
    float acc = 0.f;
    const float* W = Wg + (size_t)hd * 64 * 128;
    #pragma unroll 8
    for (int i = 0; i < 64; i++) acc += hr[i] * W[i * 128 + t];
    Wh[(size_t)(hd * 512 + n) * 128 + t] = acc;
    float ps = wave_sum(acc * asrc[hd * 128 + t]);
    float pd = wave_sum(acc * adst[hd * 128 + t]);
    if ((t & 63) == 0) { r0[t >> 6] = ps; r1[t >> 6] = pd; }
    __syncthreads();
    if (t == 0) { es[hd * 512 + n] = r0[0] + r0[1]; ed[hd * 512 + n] = r1[0] + r1[1]; }
}

// ---------------- K4: ve1[h,i] = sum_o Weg[h,i,o]*a_edge[h,o] ----------------
// grid 16, block 64
__global__ void k_ve1(const float* __restrict__ Weg, const float* __restrict__ ae,
                      float* __restrict__ ve1) {
    int hd = blockIdx.x, i = threadIdx.x;
    float acc = 0.f;
    for (int o = 0; o < 128; o++) acc += Weg[((size_t)hd * 64 + i) * 128 + o] * ae[hd * 128 + o];
    ve1[hd * 64 + i] = acc;
}

// ---------------- K4b: ve2[c] = sum_o Weo[c,o]*ao_edge[o] ----------------
// grid 16, block 128
__global__ void k_ve2(const float* __restrict__ Weo, const float* __restrict__ aoe,
                      float* __restrict__ ve2) {
    int c = blockIdx.x * 128 + threadIdx.x;
    float acc = 0.f;
    for (int o = 0; o < 128; o++) acc += Weo[(size_t)c * 128 + o] * aoe[o];
    ve2[c] = acc;
}

// ---------------- K5: scatter last-wins winner edge per (src/2, dst/2) slot ----------------
// grid 16, block 256
__global__ void k_scatter(const int* __restrict__ ei, int* __restrict__ winner) {
    int e = blockIdx.x * 256 + threadIdx.x;
    if (e < 4096) {
        int s = ei[e] >> 1;
        int d = ei[4096 + e] >> 1;
        atomicMax(&winner[s * 256 + d], e);   // last edge index wins (np .set semantics)
    }
}

// ---------------- K6: GAT1 attention rows, wave-parallel softmax (2 heads/wave) ----------------
// grid 512 (s), block 512
__global__ void k_attn1(const float* __restrict__ es, const float* __restrict__ ed,
                        const float* __restrict__ adj, const float* __restrict__ n2n,
                        const float* __restrict__ ve1, float* __restrict__ attn) {
    int s = blockIdx.x, d = threadIdx.x;
    __shared__ float vl[16][64];     // 4KB
    __shared__ float esh[16][512];   // 32KB
    __shared__ float esr[16];
    for (int idx = d; idx < 16 * 64; idx += 512) vl[idx >> 6][idx & 63] = ve1[idx];
    if (d < 16) esr[d] = es[d * 512 + s];
    __syncthreads();
    float a = adj[s * 512 + d];
    if (a > 0.f) {
        const float* row = n2n + (size_t)(s * 512 + d) * 64;
        float ee[16];
        #pragma unroll
        for (int hd = 0; hd < 16; hd++) ee[hd] = 0.f;
        for (int i = 0; i < 64; i++) {
            float r = row[i];
            #pragma unroll
            for (int hd = 0; hd < 16; hd++) ee[hd] += r * vl[hd][i];
        }
        #pragma unroll
        for (int hd = 0; hd < 16; hd++)
            esh[hd][d] = lrelu(esr[hd] + ed[hd * 512 + d] + ee[hd]);
    } else {
        #pragma unroll
        for (int hd = 0; hd < 16; hd++) esh[hd][d] = NEGF;
    }
    __syncthreads();
    int w = d >> 6, l = d & 63;
    #pragma unroll
    for (int j = 0; j < 2; j++) {
        int hd = 2 * w + j;
        float v[8];
        #pragma unroll
        for (int k = 0; k < 8; k++) v[k] = esh[hd][l + 64 * k];
        float m = v[0];
        #pragma unroll
        for (int k = 1; k < 8; k++) m = fmaxf(m, v[k]);
        m = wave_max(m);
        float p[8], Z = 0.f;
        #pragma unroll
        for (int k = 0; k < 8; k++) { p[k] = expf(v[k] - m); Z += p[k]; }
        Z = wave_sum(Z);
        float inv = 1.f / Z;
        float* dst = attn + ((size_t)(hd * 512 + s)) * 512;
        #pragma unroll
        for (int k = 0; k < 8; k++) dst[l + 64 * k] = p[k] * inv;
    }
}

// ---------------- K7: hout = elu(attn @ Wh), 8 source rows per block ----------------
// grid (64, 16), block 128
__global__ void k_hout1(const float* __restrict__ attn, const float* __restrict__ Wh,
                        float* __restrict__ hout) {
    int st = blockIdx.x, hd = blockIdx.y, t = threadIdx.x;
    __shared__ float at[8][512];
    int s0 = st * 8;
    for (int idx = t; idx < 8 * 512; idx += 128) {
        int r = idx >> 9, d = idx & 511;
        at[r][d] = attn[((size_t)(hd * 512 + s0 + r)) * 512 + d];
    }
    __syncthreads();
    float acc[8] = {0, 0, 0, 0, 0, 0, 0, 0};
    const float* W = Wh + (size_t)hd * 512 * 128;
    for (int d = 0; d < 512; d++) {
        float w = W[(size_t)d * 128 + t];
        #pragma unroll
        for (int r = 0; r < 8; r++) acc[r] += at[r][d] * w;
    }
    #pragma unroll
    for (int r = 0; r < 8; r++)
        hout[(size_t)(s0 + r) * 2048 + hd * 128 + t] = eluf(acc[r]);
}

// ---------------- K8: per-edge d2[e] = sum_c elu(edge_attr[e] @ Weg)[c] * ve2[c] ----------------
// grid 512 (8 edges/block), block 256
__global__ void k_edot(const float* __restrict__ eattr, const float* __restrict__ Weg,
                       const float* __restrict__ ve2, float* __restrict__ d2) {
    int e0 = blockIdx.x * 8, t = threadIdx.x;
    int w = t >> 6, l = t & 63;
    __shared__ float ea[8][64];
    __shared__ float sd[8][4];
    for (int idx = t; idx < 8 * 64; idx += 256)
        ea[idx >> 6][idx & 63] = eattr[(size_t)(e0 + (idx >> 6)) * 64 + (idx & 63)];
    __syncthreads();
    int hd = t >> 4, o0 = (t & 15) * 8;
    float acc[8][8];
    #pragma unroll
    for (int r = 0; r < 8; r++)
        #pragma unroll
        for (int j = 0; j < 8; j++) acc[r][j] = 0.f;
    const float* W = Weg + (size_t)hd * 64 * 128 + o0;
    for (int i = 0; i < 64; i++) {
        float wv[8];
        #pragma unroll
        for (int j = 0; j < 8; j++) wv[j] = W[i * 128 + j];
        #pragma unroll
        for (int r = 0; r < 8; r++) {
            float a = ea[r][i];
            #pragma unroll
            for (int j = 0; j < 8; j++) acc[r][j] += a * wv[j];
        }
    }
    float v2[8];
    #pragma unroll
    for (int j = 0; j < 8; j++) v2[j] = ve2[hd * 128 + o0 + j];
    #pragma unroll
    for (int r = 0; r < 8; r++) {
        float p = 0.f;
        #pragma unroll
        for (int j = 0; j < 8; j++) p += eluf(acc[r][j]) * v2[j];
        p = wave_sum(p);
        if (l == 0) sd[r][w] = p;
    }
    __syncthreads();
    if (t < 8) d2[e0 + t] = sd[t][0] + sd[t][1] + sd[t][2] + sd[t][3];
}

// ---------------- K9: edge_pool1 ----------------
// grid 256, block 256
__global__ void k_pool1(const float* __restrict__ x, const float* __restrict__ Wp,
                        const float* __restrict__ bp, float* __restrict__ xo) {
    int k = blockIdx.x, t = threadIdx.x, w = t >> 6, l = t & 63;
    __shared__ float sd[4];
    float p = 0.f;
    for (int f = t; f < 2048; f += 256)
        p += x[(size_t)(2 * k) * 2048 + f] * Wp[f] + x[(size_t)(2 * k + 1) * 2048 + f] * Wp[2048 + f];
    p = wave_sum(p);
    if (l == 0) sd[w] = p;
    __syncthreads();
    float sc = sigm(sd[0] + sd[1] + sd[2] + sd[3] + bp[0]);
    for (int f = t; f < 2048; f += 256)
        xo[(size_t)k * 2048 + f] = (x[(size_t)(2 * k) * 2048 + f] + x[(size_t)(2 * k + 1) * 2048 + f]) * sc;
}

// ---------------- gate2[n] = sigm(x1p[n]·g2W + b), block per node ----------------
// grid 256, block 256
__global__ void k_gate2(const float* __restrict__ x, const float* __restrict__ gW,
                        const float* __restrict__ gb, float* __restrict__ gate) {
    int n = blockIdx.x, t = threadIdx.x, w = t >> 6, l = t & 63;
    __shared__ float sd[4];
    float p = 0.f;
    #pragma unroll
    for (int k = 0; k < 8; k++) {
        int c = t + 256 * k;
        p += x[(size_t)n * 2048 + c] * gW[c];
    }
    p = wave_sum(p);
    if (l == 0) sd[w] = p;
    __syncthreads();
    if (t == 0) gate[n] = sigm(sd[0] + sd[1] + sd[2] + sd[3] + gb[0]);
}

// ---------------- wsum2: out[64+c] = sum_n softmax(gate2)[n]*x[n,c] ----------------
// grid 8, block 256
__global__ void k_wsum2(const float* __restrict__ x, const float* __restrict__ gate,
                        float* __restrict__ out) {
    int t = threadIdx.x, w = t >> 6, l = t & 63;
    __shared__ float mx[4], sm[4], al[256];
    float g = gate[t];
    float m = wave_max(g);
    if (l == 0) mx[w] = m;
    __syncthreads();
    m = fmaxf(fmaxf(mx[0], mx[1]), fmaxf(mx[2], mx[3]));
    float p = expf(g - m);
    float Z = wave_sum(p);
    if (l == 0) sm[w] = Z;
    __syncthreads();
    Z = sm[0] + sm[1] + sm[2] + sm[3];
    al[t] = p / Z;
    __syncthreads();
    int c = blockIdx.x * 256 + t;
    float acc = 0.f;
    for (int n = 0; n < 256; n++) acc += al[n] * x[(size_t)n * 2048 + c];
    out[64 + c] = acc;
}

// ---------------- K11: Wh2 = x1p @ Wo, es2/ed2 — K-split, 16 waves/block ----------------
// grid 256, block 1024: t = ks*128 + c, ks in [0,8), each accumulates 256 K-elems
__global__ void k_wh2(const float* __restrict__ x, const float* __restrict__ Wo,
                      const float* __restrict__ aos, const float* __restrict__ aod,
                      float* __restrict__ Wh2, float* __restrict__ es2, float* __restrict__ ed2) {
    int n = blockIdx.x, t = threadIdx.x;
    int ks = t >> 7, c = t & 127;
    __shared__ float xr[2048];       // 8KB
    __shared__ float part[8][128];   // 4KB
    __shared__ float r0[2], r1[2];
    for (int i = t; i < 2048; i += 1024) xr[i] = x[(size_t)n * 2048 + i];
    __syncthreads();
    float acc = 0.f;
    const float* W = Wo + (size_t)(ks * 256) * 128 + c;
    const float* xk = xr + ks * 256;
    #pragma unroll 8
    for (int i = 0; i < 256; i++) acc += xk[i] * W[(size_t)i * 128];
    part[ks][c] = acc;
    __syncthreads();
    float a = 0.f;
    if (t < 128) {
        #pragma unroll
        for (int k = 0; k < 8; k++) a += part[k][t];
        Wh2[n * 128 + t] = a;
    }
    float ps = (t < 128) ? a * aos[t] : 0.f;
    float pd = (t < 128) ? a * aod[t] : 0.f;
    ps = wave_sum(ps);
    pd = wave_sum(pd);
    if (t < 128 && (t & 63) == 0) { r0[t >> 6] = ps; r1[t >> 6] = pd; }
    __syncthreads();
    if (t == 0) { es2[n] = r0[0] + r0[1]; ed2[n] = r1[0] + r1[1]; }
}

// ---------------- K12: GAT2 attention + hout2 ----------------
// grid 256, block 256
__global__ void k_attn2(const int* __restrict__ winner, const float* __restrict__ d2,
                        const float* __restrict__ es2, const float* __restrict__ ed2,
                        const float* __restrict__ Wh2, float* __restrict__ hout2) {
    int s = blockIdx.x, t = threadIdx.x, w = t >> 6, l = t & 63;
    __shared__ float mx[4], sm[4], at[256];
    int win = winner[s * 256 + t];
    float e;
    if (win >= 0) e = lrelu(es2[s] + ed2[t] + d2[win]);
    else e = NEGF;
    float m = wave_max(e);
    if (l == 0) mx[w] = m;
    __syncthreads();
    m = fmaxf(fmaxf(mx[0], mx[1]), fmaxf(mx[2], mx[3]));
    float p = expf(e - m);
    float Z = wave_sum(p);
    if (l == 0) sm[w] = Z;
    __syncthreads();
    Z = sm[0] + sm[1] + sm[2] + sm[3];
    at[t] = p / Z;
    __syncthreads();
    if (t < 128) {
        float acc = 0.f;
        for (int d = 0; d < 256; d++) acc += at[d] * Wh2[d * 128 + t];
        hout2[s * 128 + t] = acc;   // concat=False: no elu
    }
}

// ---------------- K13: edge_pool2 ----------------
// grid 128, block 128
__global__ void k_pool2(const float* __restrict__ x, const float* __restrict__ Wp,
                        const float* __restrict__ bp, float* __restrict__ xo) {
    int k = blockIdx.x, t = threadIdx.x;
    __shared__ float r[2];
    float a0 = x[(size_t)(2 * k) * 128 + t];
    float a1 = x[(size_t)(2 * k + 1) * 128 + t];
    float p = wave_sum(a0 * Wp[t] + a1 * Wp[128 + t]);
    if ((t & 63) == 0) r[t >> 6] = p;
    __syncthreads();
    float sc = sigm(r[0] + r[1] + bp[0]);
    xo[k * 128 + t] = (a0 + a1) * sc;
}

// ---------------- gate3[n] = sigm(x2p[n]·g3W + b), wave per node ----------------
// grid 32, block 256
__global__ void k_gate3(const float* __restrict__ x, const float* __restrict__ gW,
                        const float* __restrict__ gb, float* __restrict__ gate) {
    int node = blockIdx.x * 4 + (threadIdx.x >> 6), l = threadIdx.x & 63;
    float v = x[node * 128 + l] * gW[l] + x[node * 128 + 64 + l] * gW[64 + l];
    v = wave_sum(v);
    if (l == 0) gate[node] = sigm(v + gb[0]);
}

// ---------------- wsum3: out[2112+c] = sum_n softmax(gate3)[n]*x[n,c] ----------------
// grid 1, block 128
__global__ void k_wsum3(const float* __restrict__ x, const float* __restrict__ gate,
                        float* __restrict__ out) {
    int t = threadIdx.x, w = t >> 6, l = t & 63;
    __shared__ float mx[2], sm[2], al[128];
    float g = gate[t];
    float m = wave_max(g);
    if (l == 0) mx[w] = m;
    __syncthreads();
    m = fmaxf(mx[0], mx[1]);
    float p = expf(g - m);
    float Z = wave_sum(p);
    if (l == 0) sm[w] = Z;
    __syncthreads();
    Z = sm[0] + sm[1];
    al[t] = p / Z;
    __syncthreads();
    float acc = 0.f;
    for (int n = 0; n < 128; n++) acc += al[n] * x[n * 128 + t];
    out[2112 + t] = acc;
}

extern "C" void kernel_launch(void* const* d_in, const int* in_sizes, int n_in,
                              void* d_out, int out_size, void* d_ws, size_t ws_size,
                              hipStream_t stream) {
    const float* feat  = (const float*)d_in[0];
    const int*   eidx  = (const int*)d_in[1];
    const float* eattr = (const float*)d_in[2];
    const float* adj   = (const float*)d_in[3];
    const float* n2n   = (const float*)d_in[4];
    const float* Wsn   = (const float*)d_in[5];
    const float* asn   = (const float*)d_in[6];
    const float* Wg    = (const float*)d_in[7];
    const float* Weg   = (const float*)d_in[8];
    const float* asrc  = (const float*)d_in[9];
    const float* adst  = (const float*)d_in[10];
    const float* aedge = (const float*)d_in[11];
    const float* Wp1   = (const float*)d_in[12];
    const float* bp1   = (const float*)d_in[13];
    const float* Wo    = (const float*)d_in[14];
    const float* Weo   = (const float*)d_in[15];
    const float* aos   = (const float*)d_in[16];
    const float* aod   = (const float*)d_in[17];
    const float* aoe   = (const float*)d_in[18];
    const float* Wp2   = (const float*)d_in[19];
    const float* bp2   = (const float*)d_in[20];
    const float* g1W   = (const float*)d_in[21];
    const float* g1b   = (const float*)d_in[22];
    const float* g2W   = (const float*)d_in[23];
    const float* g2b   = (const float*)d_in[24];
    const float* g3W   = (const float*)d_in[25];
    const float* g3b   = (const float*)d_in[26];
    float* out = (float*)d_out;

    char* ws = (char*)d_ws;
    float* h      = (float*)(ws + 0x0000000);   // 128KB
    float* Wh1    = (float*)(ws + 0x0020000);   // 4MB
    float* es1    = (float*)(ws + 0x0420000);   // 32KB
    float* ed1    = (float*)(ws + 0x0428000);   // 32KB
    float* ve1    = (float*)(ws + 0x0430000);   // 4KB
    float* ve2    = (float*)(ws + 0x0431000);   // 8KB
    float* gate1  = (float*)(ws + 0x0433000);   // 2KB
    float* gate2  = (float*)(ws + 0x0434000);   // 1KB
    float* gate3  = (float*)(ws + 0x0435000);   // 0.5KB
    float* attn   = (float*)(ws + 0x0440000);   // 16MB
    float* hout1  = (float*)(ws + 0x1440000);   // 4MB
    float* d2     = (float*)(ws + 0x1840000);   // 16KB
    float* x1p    = (float*)(ws + 0x1850000);   // 2MB
    int*   winner = (int*)  (ws + 0x1A50000);   // 256KB
    float* Wh2    = (float*)(ws + 0x1A90000);   // 128KB
    float* es2    = (float*)(ws + 0x1AB0000);   // 1KB
    float* ed2    = (float*)(ws + 0x1AB1000);   // 1KB
    float* hout2  = (float*)(ws + 0x1AB2000);   // 128KB
    float* x2p    = (float*)(ws + 0x1AD2000);   // 64KB

    hipMemsetAsync(winner, 0xFF, 65536 * sizeof(int), stream);   // winner = -1

    k_sn     <<<512, 64, 0, stream>>>(feat, Wsn, asn, h);
    k_ve1    <<<16, 64, 0, stream>>>(Weg, aedge, ve1);
    k_ve2    <<<16, 128, 0, stream>>>(Weo, aoe, ve2);
    k_scatter<<<16, 256, 0, stream>>>(eidx, winner);
    k_gate1  <<<128, 256, 0, stream>>>(h, g1W, g1b, gate1);
    k_wsum1  <<<1, 512, 0, stream>>>(h, gate1, out);
    k_gat1_wh<<<dim3(512, 16), 128, 0, stream>>>(h, Wg, asrc, adst, Wh1, es1, ed1);
    k_attn1  <<<512, 512, 0, stream>>>(es1, ed1, adj, n2n, ve1, attn);
    k_hout1  <<<dim3(64, 16), 128, 0, stream>>>(attn, Wh1, hout1);
    k_edot   <<<512, 256, 0, stream>>>(eattr, Weg, ve2, d2);
    k_pool1  <<<256, 256, 0, stream>>>(hout1, Wp1, bp1, x1p);
    k_gate2  <<<256, 256, 0, stream>>>(x1p, g2W, g2b, gate2);
    k_wsum2  <<<8, 256, 0, stream>>>(x1p, gate2, out);
    k_wh2    <<<256, 1024, 0, stream>>>(x1p, Wo, aos, aod, Wh2, es2, ed2);
    k_attn2  <<<256, 256, 0, stream>>>(winner, d2, es2, ed2, Wh2, hout2);
    k_pool2  <<<128, 128, 0, stream>>>(hout2, Wp2, bp2, x2p);
    k_gate3  <<<32, 256, 0, stream>>>(x2p, g3W, g3b, gate3);
    k_wsum3  <<<1, 128, 0, stream>>>(x2p, gate3, out);
}